// Round 1
// baseline (28460.107 us; speedup 1.0000x reference)
//
#include <hip/hip_runtime.h>
#include <hip/hip_bf16.h>

#define NNODE  65536   // 2*B*S
#define NEDGE  524288  // 2*B*EPG
#define NGRAPH 512     // 2*B
#define EPG    1024
#define NPROP  5
#define SINKI  20

// ---------------- single-layer encoder: y = x@W + b ----------------
template<int IN, int OUT>
__global__ void enc_kernel(const float* __restrict__ x, const float* __restrict__ W,
                           const float* __restrict__ b, float* __restrict__ y, int rows) {
    int idx = blockIdx.x * blockDim.x + threadIdx.x;
    if (idx >= rows * OUT) return;
    int r = idx / OUT, o = idx % OUT;
    const float* xr = x + (size_t)r * IN;
    float acc = b[o];
#pragma unroll
    for (int k = 0; k < IN; ++k) acc = fmaf(xr[k], W[k * OUT + o], acc);
    y[idx] = acc;
}

// ---------------- 2-layer MLP: y = relu([x1||x2]@W1+b1)@W2+b2 ----------------
template<int IN1, int IN2, int HID, int OUT>
__global__ __launch_bounds__(256) void mlp2_kernel(
    const float* __restrict__ x1, const float* __restrict__ x2,
    const float* __restrict__ W1, const float* __restrict__ b1,
    const float* __restrict__ W2, const float* __restrict__ b2,
    float* __restrict__ y) {
    constexpr int IN = IN1 + IN2;
    constexpr int TR = 64;
    __shared__ float xs[TR][IN];
    __shared__ float hs[TR][HID];
    const int t = threadIdx.x;
    const int row0 = blockIdx.x * TR;

    constexpr int INQ = IN / 4;
    for (int idx = t; idx < TR * INQ; idx += 256) {
        int r = idx / INQ, k0 = (idx % INQ) * 4;
        float4 v;
        if (IN2 == 0 || k0 < IN1) v = *(const float4*)(x1 + (size_t)(row0 + r) * IN1 + k0);
        else                      v = *(const float4*)(x2 + (size_t)(row0 + r) * IN2 + (k0 - IN1));
        *(float4*)&xs[r][k0] = v;
    }
    __syncthreads();

    constexpr int HQ = HID / 4;
    for (int idx = t; idx < TR * HQ; idx += 256) {
        int r = idx / HQ, j0 = (idx % HQ) * 4;
        float a0 = b1[j0], a1 = b1[j0+1], a2 = b1[j0+2], a3 = b1[j0+3];
        const float* wp = W1 + j0;
#pragma unroll 8
        for (int k = 0; k < IN; ++k) {
            float xv = xs[r][k];
            float4 w = *(const float4*)(wp + k * HID);
            a0 = fmaf(xv, w.x, a0); a1 = fmaf(xv, w.y, a1);
            a2 = fmaf(xv, w.z, a2); a3 = fmaf(xv, w.w, a3);
        }
        hs[r][j0]   = fmaxf(a0, 0.f); hs[r][j0+1] = fmaxf(a1, 0.f);
        hs[r][j0+2] = fmaxf(a2, 0.f); hs[r][j0+3] = fmaxf(a3, 0.f);
    }
    __syncthreads();

    constexpr int OQ = OUT / 4;
    for (int idx = t; idx < TR * OQ; idx += 256) {
        int r = idx / OQ, d0 = (idx % OQ) * 4;
        float a0 = b2[d0], a1 = b2[d0+1], a2 = b2[d0+2], a3 = b2[d0+3];
        const float* wp = W2 + d0;
#pragma unroll 8
        for (int k = 0; k < HID; ++k) {
            float hv = hs[r][k];
            float4 w = *(const float4*)(wp + k * OUT);
            a0 = fmaf(hv, w.x, a0); a1 = fmaf(hv, w.y, a1);
            a2 = fmaf(hv, w.z, a2); a3 = fmaf(hv, w.w, a3);
        }
        *(float4*)(y + (size_t)(row0 + r) * OUT + d0) = make_float4(a0, a1, a2, a3);
    }
}

// ---------------- per-graph message MLP + LDS segment-sum ----------------
// block g handles graph g: 1024 edges, 128 nodes. 512 threads.
// thread -> (esub 0..7, dir 0..1, 4 hidden/out columns j0..j0+3)
__global__ __launch_bounds__(512) void msg_kernel(
    const float* __restrict__ c, const float* __restrict__ e_enc,
    const int* __restrict__ from_idx, const int* __restrict__ to_idx,
    const float* __restrict__ W1, const float* __restrict__ b1,
    const float* __restrict__ W2, const float* __restrict__ b2,
    float* __restrict__ agg) {
    __shared__ float cs[128][64];    // 32 KB
    __shared__ float ag[128][128];   // 64 KB
    __shared__ float hid[2][16][128];// 16 KB (double-buffered)
    const int g = blockIdx.x;
    const int t = threadIdx.x;

    const float* cblk = c + (size_t)g * 128 * 64;
    for (int idx = t; idx < 2048; idx += 512)
        ((float4*)cs)[idx] = ((const float4*)cblk)[idx];
    for (int idx = t; idx < 4096; idx += 512)
        ((float4*)ag)[idx] = make_float4(0.f, 0.f, 0.f, 0.f);
    __syncthreads();

    const int grp  = t >> 5;    // 0..15
    const int esub = grp >> 1;  // 0..7
    const int dir  = grp & 1;
    const int j0   = (t & 31) * 4;
    const float b1x = b1[j0], b1y = b1[j0+1], b1z = b1[j0+2], b1w = b1[j0+3];
    const float b2x = b2[j0], b2y = b2[j0+1], b2z = b2[j0+2], b2w = b2[j0+3];
    const int ebase = g * EPG;
    const int nbase = g * 128;

    for (int es = 0; es < EPG; es += 8) {
        const int buf = (es >> 3) & 1;
        const int e  = ebase + es + esub;
        const int f  = from_idx[e] - nbase;
        const int tt = to_idx[e]  - nbase;
        const int rowA = dir ? tt : f;   // first 64 rows of W1
        const int rowB = dir ? f : tt;   // next 64 rows of W1
        float a0 = b1x, a1 = b1y, a2 = b1z, a3 = b1w;
        const float* wp = W1 + j0;
#pragma unroll 4
        for (int k = 0; k < 64; ++k) {
            float xv = cs[rowA][k];
            float4 w = *(const float4*)(wp + k * 128);
            a0 = fmaf(xv, w.x, a0); a1 = fmaf(xv, w.y, a1);
            a2 = fmaf(xv, w.z, a2); a3 = fmaf(xv, w.w, a3);
        }
#pragma unroll 4
        for (int k = 0; k < 64; ++k) {
            float xv = cs[rowB][k];
            float4 w = *(const float4*)(wp + (64 + k) * 128);
            a0 = fmaf(xv, w.x, a0); a1 = fmaf(xv, w.y, a1);
            a2 = fmaf(xv, w.z, a2); a3 = fmaf(xv, w.w, a3);
        }
        const float* ep = e_enc + (size_t)e * 32;
#pragma unroll 4
        for (int k = 0; k < 32; ++k) {
            float xv = ep[k];
            float4 w = *(const float4*)(wp + (128 + k) * 128);
            a0 = fmaf(xv, w.x, a0); a1 = fmaf(xv, w.y, a1);
            a2 = fmaf(xv, w.z, a2); a3 = fmaf(xv, w.w, a3);
        }
        float4 hv4 = make_float4(fmaxf(a0,0.f), fmaxf(a1,0.f), fmaxf(a2,0.f), fmaxf(a3,0.f));
        *(float4*)&hid[buf][grp][j0] = hv4;
        __syncthreads();
        // layer 2
        float m0 = b2x, m1 = b2y, m2 = b2z, m3 = b2w;
        const float* w2p = W2 + j0;
#pragma unroll 4
        for (int k = 0; k < 128; ++k) {
            float hv = hid[buf][grp][k];
            float4 w = *(const float4*)(w2p + k * 128);
            m0 = fmaf(hv, w.x, m0); m1 = fmaf(hv, w.y, m1);
            m2 = fmaf(hv, w.z, m2); m3 = fmaf(hv, w.w, m3);
        }
        const int dest = dir ? f : tt;   // m_f -> to, m_r -> from
        atomicAdd(&ag[dest][j0],   m0);
        atomicAdd(&ag[dest][j0+1], m1);
        atomicAdd(&ag[dest][j0+2], m2);
        atomicAdd(&ag[dest][j0+3], m3);
        // next iter's layer-1 writes the other hid buffer; its __syncthreads
        // orders this iter's reads before the buffer is reused.
    }
    __syncthreads();
    float* aout = agg + (size_t)g * 128 * 128;
    for (int idx = t; idx < 4096; idx += 512)
        ((float4*)aout)[idx] = ((const float4*)ag)[idx];
}

// ---------------- per-pair: sim -> sinkhorn -> T-apply -> store (+score) ----------------
__global__ __launch_bounds__(256) void sink_kernel(
    const float* __restrict__ tbuf, const float* __restrict__ h,
    float* __restrict__ store, float* __restrict__ scores, int do_score) {
    __shared__ float la[128][128];      // 64 KB: log_a then T
    __shared__ float ub[2 * 128 * 66];  // 67.6 KB union: (tq,tc)[128][33] then (hq,hc)[128][66]
    __shared__ float pm[256], ps[256];
    const int p = blockIdx.x, t = threadIdx.x;

    // load transformed q/c (stride 33 to avoid bank conflicts on column reads)
    const float* tq_src = tbuf + (size_t)(2 * p)     * 128 * 32;
    const float* tc_src = tbuf + (size_t)(2 * p + 1) * 128 * 32;
    for (int idx = t; idx < 4096; idx += 256) {
        int i = idx >> 5, k = idx & 31;
        ub[i * 33 + k]            = tq_src[idx];
        ub[128 * 33 + i * 33 + k] = tc_src[idx];
    }
    __syncthreads();

    // sim / TEMP
    for (int idx = t; idx < 16384; idx += 256) {
        int i = idx >> 7, j = idx & 127;
        float acc = 0.f;
#pragma unroll
        for (int k = 0; k < 32; ++k)
            acc = fmaf(ub[i * 33 + k], ub[128 * 33 + j * 33 + k], acc);
        la[i][j] = acc * 10.f;   // 1/TEMP
    }
    __syncthreads();

    const int w = t >> 6, l = t & 63;
    for (int iter = 0; iter < SINKI; ++iter) {
        // row logsumexp (axis=2): one wave per row, 2 elems/lane
        for (int r = w; r < 128; r += 4) {
            float a0 = la[r][l], a1 = la[r][l + 64];
            float mx = fmaxf(a0, a1);
#pragma unroll
            for (int off = 32; off >= 1; off >>= 1) mx = fmaxf(mx, __shfl_xor(mx, off));
            float s = __expf(a0 - mx) + __expf(a1 - mx);
#pragma unroll
            for (int off = 32; off >= 1; off >>= 1) s += __shfl_xor(s, off);
            float lse = mx + __logf(s);
            la[r][l]      = a0 - lse;
            la[r][l + 64] = a1 - lse;
        }
        __syncthreads();
        // column logsumexp (axis=1): 2 half-columns per column
        const int j = t & 127, hh = t >> 7, i0 = hh * 64;
        float mx = -INFINITY;
        for (int i = i0; i < i0 + 64; ++i) mx = fmaxf(mx, la[i][j]);
        pm[t] = mx;
        __syncthreads();
        const float M = fmaxf(pm[j], pm[128 + j]);
        float s = 0.f;
        for (int i = i0; i < i0 + 64; ++i) s += __expf(la[i][j] - M);
        ps[t] = s;
        __syncthreads();
        const float lse = M + __logf(ps[j] + ps[128 + j]);
        for (int i = i0; i < i0 + 64; ++i) la[i][j] -= lse;
        __syncthreads();
    }

    // T = exp(la)  (each thread owns its strided elements)
    for (int idx = t; idx < 16384; idx += 256)
        ((float*)la)[idx] = __expf(((float*)la)[idx]);
    // load raw h blocks (overwrites tq/tc region; last read was sim phase)
    const float* hq_src = h + (size_t)(2 * p)     * 128 * 64;
    const float* hc_src = h + (size_t)(2 * p + 1) * 128 * 64;
    for (int idx = t; idx < 8192; idx += 256) {
        int i = idx >> 6, d = idx & 63;
        ub[i * 66 + d]            = hq_src[idx];
        ub[128 * 66 + i * 66 + d] = hc_src[idx];
    }
    __syncthreads();

    float sc = 0.f;
    float* store_q = store + (size_t)(2 * p)     * 128 * 64;
    float* store_c = store + (size_t)(2 * p + 1) * 128 * 64;
    // q_from_c = T @ hc ; score terms relu(hq - q_from_c)
    for (int idx = t; idx < 8192; idx += 256) {
        int i = idx >> 6, d = idx & 63;
        float acc = 0.f;
#pragma unroll 8
        for (int j = 0; j < 128; ++j)
            acc = fmaf(la[i][j], ub[128 * 66 + j * 66 + d], acc);
        store_q[idx] = acc;
        if (do_score) sc += fmaxf(ub[i * 66 + d] - acc, 0.f);
    }
    // c_from_q = T^T @ hq
    for (int idx = t; idx < 8192; idx += 256) {
        int j = idx >> 6, d = idx & 63;
        float acc = 0.f;
#pragma unroll 8
        for (int i = 0; i < 128; ++i)
            acc = fmaf(la[i][j], ub[i * 66 + d], acc);
        store_c[idx] = acc;
    }
    if (do_score) {
#pragma unroll
        for (int off = 32; off >= 1; off >>= 1) sc += __shfl_xor(sc, off);
        if (l == 0) pm[w] = sc;
        __syncthreads();
        if (t == 0) scores[p] = -(pm[0] + pm[1] + pm[2] + pm[3]);
    }
}

extern "C" void kernel_launch(void* const* d_in, const int* in_sizes, int n_in,
                              void* d_out, int out_size, void* d_ws, size_t ws_size,
                              hipStream_t stream) {
    const float* node_features = (const float*)d_in[0];
    const float* edge_features = (const float*)d_in[1];
    const float* W_enc_n = (const float*)d_in[2];
    const float* b_enc_n = (const float*)d_in[3];
    const float* W_enc_e = (const float*)d_in[4];
    const float* b_enc_e = (const float*)d_in[5];
    const float* W_c1 = (const float*)d_in[6];
    const float* b_c1 = (const float*)d_in[7];
    const float* W_c2 = (const float*)d_in[8];
    const float* b_c2 = (const float*)d_in[9];
    const float* W_m1 = (const float*)d_in[10];
    const float* b_m1 = (const float*)d_in[11];
    const float* W_m2 = (const float*)d_in[12];
    const float* b_m2 = (const float*)d_in[13];
    const float* W_u1 = (const float*)d_in[14];
    const float* b_u1 = (const float*)d_in[15];
    const float* W_u2 = (const float*)d_in[16];
    const float* b_u2 = (const float*)d_in[17];
    const float* W_t1 = (const float*)d_in[18];
    const float* b_t1 = (const float*)d_in[19];
    const float* W_t2 = (const float*)d_in[20];
    const float* b_t2 = (const float*)d_in[21];
    const int* from_idx = (const int*)d_in[22];
    const int* to_idx   = (const int*)d_in[23];
    float* scores = (float*)d_out;

    char* ws = (char*)d_ws;
    size_t off = 0;
    auto alloc = [&](size_t nfloats) { float* pp = (float*)(ws + off); off += nfloats * sizeof(float); return pp; };
    float* h    = alloc((size_t)NNODE * 64);
    float* st   = alloc((size_t)NNODE * 64);
    float* cbuf = alloc((size_t)NNODE * 64);
    float* aggb = alloc((size_t)NNODE * 128);
    float* tb   = alloc((size_t)NNODE * 32);
    float* eenc = alloc((size_t)NEDGE * 32);
    (void)ws_size; (void)in_sizes; (void)n_in; (void)out_size;

    hipMemsetAsync(st, 0, (size_t)NNODE * 64 * sizeof(float), stream);
    enc_kernel<16, 64><<<(NNODE * 64 + 255) / 256, 256, 0, stream>>>(node_features, W_enc_n, b_enc_n, h, NNODE);
    enc_kernel<8, 32><<<(NEDGE * 32 + 255) / 256, 256, 0, stream>>>(edge_features, W_enc_e, b_enc_e, eenc, NEDGE);

    for (int it = 0; it < NPROP; ++it) {
        mlp2_kernel<64, 64, 128, 64><<<NNODE / 64, 256, 0, stream>>>(h, st, W_c1, b_c1, W_c2, b_c2, cbuf);
        msg_kernel<<<NGRAPH, 512, 0, stream>>>(cbuf, eenc, from_idx, to_idx, W_m1, b_m1, W_m2, b_m2, aggb);
        mlp2_kernel<64, 128, 128, 64><<<NNODE / 64, 256, 0, stream>>>(cbuf, aggb, W_u1, b_u1, W_u2, b_u2, h);
        mlp2_kernel<64, 0, 32, 32><<<NNODE / 64, 256, 0, stream>>>(h, nullptr, W_t1, b_t1, W_t2, b_t2, tb);
        sink_kernel<<<256, 256, 0, stream>>>(tb, h, st, scores, it == NPROP - 1 ? 1 : 0);
    }
}

// Round 3
// 9295.003 us; speedup vs baseline: 3.0619x; 3.0619x over previous
//
#include <hip/hip_runtime.h>
#include <hip/hip_bf16.h>

#define NNODE  65536   // 2*B*S
#define NEDGE  524288  // 2*B*EPG
#define NGRAPH 512     // 2*B
#define EPG    1024
#define NPROP  5
#define SINKI  20

typedef __attribute__((ext_vector_type(4))) float f32x4;
typedef __attribute__((ext_vector_type(8))) _Float16 f16x8;

// ---------------- single-layer encoder: y = x@W + b ----------------
template<int IN, int OUT>
__global__ void enc_kernel(const float* __restrict__ x, const float* __restrict__ W,
                           const float* __restrict__ b, float* __restrict__ y, int rows) {
    int idx = blockIdx.x * blockDim.x + threadIdx.x;
    if (idx >= rows * OUT) return;
    int r = idx / OUT, o = idx % OUT;
    const float* xr = x + (size_t)r * IN;
    float acc = b[o];
#pragma unroll
    for (int k = 0; k < IN; ++k) acc = fmaf(xr[k], W[k * OUT + o], acc);
    y[idx] = acc;
}

// ---------------- 2-layer MLP: y = relu([x1||x2]@W1+b1)@W2+b2 ----------------
template<int IN1, int IN2, int HID, int OUT>
__global__ __launch_bounds__(256) void mlp2_kernel(
    const float* __restrict__ x1, const float* __restrict__ x2,
    const float* __restrict__ W1, const float* __restrict__ b1,
    const float* __restrict__ W2, const float* __restrict__ b2,
    float* __restrict__ y) {
    constexpr int IN = IN1 + IN2;
    constexpr int TR = 64;
    __shared__ float xs[TR][IN];
    __shared__ float hs[TR][HID];
    const int t = threadIdx.x;
    const int row0 = blockIdx.x * TR;

    constexpr int INQ = IN / 4;
    for (int idx = t; idx < TR * INQ; idx += 256) {
        int r = idx / INQ, k0 = (idx % INQ) * 4;
        float4 v;
        if (IN2 == 0 || k0 < IN1) v = *(const float4*)(x1 + (size_t)(row0 + r) * IN1 + k0);
        else                      v = *(const float4*)(x2 + (size_t)(row0 + r) * IN2 + (k0 - IN1));
        *(float4*)&xs[r][k0] = v;
    }
    __syncthreads();

    constexpr int HQ = HID / 4;
    for (int idx = t; idx < TR * HQ; idx += 256) {
        int r = idx / HQ, j0 = (idx % HQ) * 4;
        float a0 = b1[j0], a1 = b1[j0+1], a2 = b1[j0+2], a3 = b1[j0+3];
        const float* wp = W1 + j0;
#pragma unroll 8
        for (int k = 0; k < IN; ++k) {
            float xv = xs[r][k];
            float4 w = *(const float4*)(wp + k * HID);
            a0 = fmaf(xv, w.x, a0); a1 = fmaf(xv, w.y, a1);
            a2 = fmaf(xv, w.z, a2); a3 = fmaf(xv, w.w, a3);
        }
        hs[r][j0]   = fmaxf(a0, 0.f); hs[r][j0+1] = fmaxf(a1, 0.f);
        hs[r][j0+2] = fmaxf(a2, 0.f); hs[r][j0+3] = fmaxf(a3, 0.f);
    }
    __syncthreads();

    constexpr int OQ = OUT / 4;
    for (int idx = t; idx < TR * OQ; idx += 256) {
        int r = idx / OQ, d0 = (idx % OQ) * 4;
        float a0 = b2[d0], a1 = b2[d0+1], a2 = b2[d0+2], a3 = b2[d0+3];
        const float* wp = W2 + d0;
#pragma unroll 8
        for (int k = 0; k < HID; ++k) {
            float hv = hs[r][k];
            float4 w = *(const float4*)(wp + k * OUT);
            a0 = fmaf(hv, w.x, a0); a1 = fmaf(hv, w.y, a1);
            a2 = fmaf(hv, w.z, a2); a3 = fmaf(hv, w.w, a3);
        }
        *(float4*)(y + (size_t)(row0 + r) * OUT + d0) = make_float4(a0, a1, a2, a3);
    }
}

// ---------------- per-graph message MLP (split-fp16 MFMA) + LDS segment-sum ----------------
// Block g: graph g. 2048 edge-dir rows = 32 tiles x 64 rows.
// 8 waves: rg=wid>>2 (32-row band), cg=wid&3 (32-col band); per wave 2 row-frags x 2 col-frags.
// Every MFMA operand is split x = hi + lo (fp16); product = Xh*Wh + Xl*Wh + Xh*Wl
// => ~2^-22 relative error (f32-class), immune to Sinkhorn's x10 log-space amplification.
union __align__(16) MsgSMem {
    struct {
        float ag[128][128];       // 64 KB  f32 aggregation (LDS atomics)
        _Float16 csh[128 * 64];   // 16 KB  c hi plane (xor-swizzled)
        _Float16 csl[128 * 64];   // 16 KB  c lo plane
        _Float16 Hh[64 * 128];    // 16 KB  hidden hi plane (xor-swizzled)
        _Float16 Hl[64 * 128];    // 16 KB  hidden lo plane
        int ef[1024];             // 4 KB   local from ids
        int et[1024];             // 4 KB   local to ids
    } run;                         // 136 KB
    _Float16 w1p[2][128 * 160];    // 80 KB  W1^T hi/lo staging
    _Float16 w2p[2][128 * 128];    // 64 KB  W2^T hi/lo staging
};

__global__ __launch_bounds__(512, 2) void msg_kernel(
    const float* __restrict__ c, const float* __restrict__ e_enc,
    const int* __restrict__ from_idx, const int* __restrict__ to_idx,
    const float* __restrict__ W1, const float* __restrict__ b1,
    const float* __restrict__ W2, const float* __restrict__ b2,
    float* __restrict__ agg) {
    __shared__ MsgSMem sm;
    const int g = blockIdx.x, t = threadIdx.x;
    const int l = t & 63, wid = t >> 6;
    const int rg = wid >> 2;          // 0..1
    const int cg = wid & 3;           // 0..3
    const int lr = l & 15;
    const int lk = (l >> 4) * 8;
    const int ebase = g * EPG, nbase = g * 128;

    // ---- phase A: stage W1^T hi/lo, hoist fragments ----
    for (int idx = t; idx < 160 * 128; idx += 512) {
        int k = idx >> 7, cc = idx & 127;
        float v = W1[idx];
        _Float16 h = (_Float16)v;
        sm.w1p[0][cc * 160 + k] = h;
        sm.w1p[1][cc * 160 + k] = (_Float16)(v - (float)h);
    }
    __syncthreads();
    f16x8 b1h[5][2], b1l[5][2];
#pragma unroll
    for (int kf = 0; kf < 5; ++kf)
#pragma unroll
        for (int cf = 0; cf < 2; ++cf) {
            const int col = cg * 32 + cf * 16 + lr;
            b1h[kf][cf] = *(const f16x8*)&sm.w1p[0][col * 160 + kf * 32 + lk];
            b1l[kf][cf] = *(const f16x8*)&sm.w1p[1][col * 160 + kf * 32 + lk];
        }
    const float b1v0 = b1[cg * 32 + lr], b1v1 = b1[cg * 32 + 16 + lr];
    __syncthreads();

    // ---- phase B: stage W2^T hi/lo, hoist fragments ----
    for (int idx = t; idx < 128 * 128; idx += 512) {
        int k = idx >> 7, cc = idx & 127;
        float v = W2[idx];
        _Float16 h = (_Float16)v;
        sm.w2p[0][cc * 128 + k] = h;
        sm.w2p[1][cc * 128 + k] = (_Float16)(v - (float)h);
    }
    __syncthreads();
    f16x8 b2h[4][2], b2l[4][2];
#pragma unroll
    for (int kf = 0; kf < 4; ++kf)
#pragma unroll
        for (int cf = 0; cf < 2; ++cf) {
            const int col = cg * 32 + cf * 16 + lr;
            b2h[kf][cf] = *(const f16x8*)&sm.w2p[0][col * 128 + kf * 32 + lk];
            b2l[kf][cf] = *(const f16x8*)&sm.w2p[1][col * 128 + kf * 32 + lk];
        }
    const float b2v0 = b2[cg * 32 + lr], b2v1 = b2[cg * 32 + 16 + lr];
    __syncthreads();

    // ---- phase C: zero ag, stage c hi/lo (swizzled), stage local edge ids ----
    for (int idx = t; idx < 4096; idx += 512)
        ((float4*)sm.run.ag)[idx] = make_float4(0.f, 0.f, 0.f, 0.f);
    {
        const float* cblk = c + (size_t)nbase * 64;
        char* cshB = (char*)sm.run.csh;
        char* cslB = (char*)sm.run.csl;
        for (int idx = t; idx < 128 * 64; idx += 512) {
            int row = idx >> 6, cc = idx & 63;
            float v = cblk[idx];
            _Float16 h = (_Float16)v;
            int byte = ((row << 7) | (cc << 1)) ^ ((row & 7) << 4);
            *(_Float16*)(cshB + byte) = h;
            *(_Float16*)(cslB + byte) = (_Float16)(v - (float)h);
        }
    }
    for (int idx = t; idx < 1024; idx += 512) {
        sm.run.ef[idx] = from_idx[ebase + idx] - nbase;
        sm.run.et[idx] = to_idx[ebase + idx] - nbase;
    }
    __syncthreads();

    char* cshB = (char*)sm.run.csh;
    char* cslB = (char*)sm.run.csl;
    char* HhB  = (char*)sm.run.Hh;
    char* HlB  = (char*)sm.run.Hl;

    for (int tile = 0; tile < 32; ++tile) {
        f32x4 acc[2][2];
        // ---- layer 1 ----
#pragma unroll
        for (int rf = 0; rf < 2; ++rf) {
            const int rloc = rg * 32 + rf * 16 + lr;
            const int R = tile * 64 + rloc;
            const int el = R >> 1, dir = R & 1;
            const int fi = sm.run.ef[el], ti = sm.run.et[el];
            const int rA = dir ? ti : fi;
            const int rB = dir ? fi : ti;
            const int swA = (rA & 7) << 4, swB = (rB & 7) << 4;
            f16x8 ah[5], al[5];
            ah[0] = *(const f16x8*)(cshB + (((rA << 7) | (lk << 1)) ^ swA));
            al[0] = *(const f16x8*)(cslB + (((rA << 7) | (lk << 1)) ^ swA));
            ah[1] = *(const f16x8*)(cshB + (((rA << 7) | ((32 + lk) << 1)) ^ swA));
            al[1] = *(const f16x8*)(cslB + (((rA << 7) | ((32 + lk) << 1)) ^ swA));
            ah[2] = *(const f16x8*)(cshB + (((rB << 7) | (lk << 1)) ^ swB));
            al[2] = *(const f16x8*)(cslB + (((rB << 7) | (lk << 1)) ^ swB));
            ah[3] = *(const f16x8*)(cshB + (((rB << 7) | ((32 + lk) << 1)) ^ swB));
            al[3] = *(const f16x8*)(cslB + (((rB << 7) | ((32 + lk) << 1)) ^ swB));
            {
                const float* eE = e_enc + (size_t)(ebase + el) * 32 + lk;
                const float4 e0 = *(const float4*)eE;
                const float4 e1 = *(const float4*)(eE + 4);
                float ev[8] = {e0.x, e0.y, e0.z, e0.w, e1.x, e1.y, e1.z, e1.w};
                f16x8 h8, l8;
#pragma unroll
                for (int j = 0; j < 8; ++j) {
                    _Float16 h = (_Float16)ev[j];
                    h8[j] = h;
                    l8[j] = (_Float16)(ev[j] - (float)h);
                }
                ah[4] = h8; al[4] = l8;
            }
            acc[rf][0] = (f32x4){b1v0, b1v0, b1v0, b1v0};
            acc[rf][1] = (f32x4){b1v1, b1v1, b1v1, b1v1};
#pragma unroll
            for (int kf = 0; kf < 5; ++kf)
#pragma unroll
                for (int cf = 0; cf < 2; ++cf) {
                    acc[rf][cf] = __builtin_amdgcn_mfma_f32_16x16x32_f16(ah[kf], b1h[kf][cf], acc[rf][cf], 0, 0, 0);
                    acc[rf][cf] = __builtin_amdgcn_mfma_f32_16x16x32_f16(al[kf], b1h[kf][cf], acc[rf][cf], 0, 0, 0);
                    acc[rf][cf] = __builtin_amdgcn_mfma_f32_16x16x32_f16(ah[kf], b1l[kf][cf], acc[rf][cf], 0, 0, 0);
                }
        }
        __syncthreads();   // prev tile's H reads complete
        // ---- relu -> hi/lo -> swizzled H planes ----
#pragma unroll
        for (int rf = 0; rf < 2; ++rf)
#pragma unroll
            for (int cf = 0; cf < 2; ++cf) {
                const int col = cg * 32 + cf * 16 + lr;
#pragma unroll
                for (int q = 0; q < 4; ++q) {
                    const int row = rg * 32 + rf * 16 + (l >> 4) * 4 + q;
                    const int byte = ((row << 8) | (col << 1)) ^ ((row & 7) << 4);
                    float v = fmaxf(acc[rf][cf][q], 0.f);
                    _Float16 h = (_Float16)v;
                    *(_Float16*)(HhB + byte) = h;
                    *(_Float16*)(HlB + byte) = (_Float16)(v - (float)h);
                }
            }
        __syncthreads();

        // ---- layer 2 + scatter ----
#pragma unroll
        for (int rf = 0; rf < 2; ++rf) {
            const int row = rg * 32 + rf * 16 + lr;
            const int sw = (row & 7) << 4;
            f16x8 xh[4], xl[4];
#pragma unroll
            for (int kf = 0; kf < 4; ++kf) {
                const int byte = ((row << 8) | ((kf * 32 + lk) << 1)) ^ sw;
                xh[kf] = *(const f16x8*)(HhB + byte);
                xl[kf] = *(const f16x8*)(HlB + byte);
            }
            f32x4 acc2[2];
            acc2[0] = (f32x4){b2v0, b2v0, b2v0, b2v0};
            acc2[1] = (f32x4){b2v1, b2v1, b2v1, b2v1};
#pragma unroll
            for (int kf = 0; kf < 4; ++kf)
#pragma unroll
                for (int cf = 0; cf < 2; ++cf) {
                    acc2[cf] = __builtin_amdgcn_mfma_f32_16x16x32_f16(xh[kf], b2h[kf][cf], acc2[cf], 0, 0, 0);
                    acc2[cf] = __builtin_amdgcn_mfma_f32_16x16x32_f16(xl[kf], b2h[kf][cf], acc2[cf], 0, 0, 0);
                    acc2[cf] = __builtin_amdgcn_mfma_f32_16x16x32_f16(xh[kf], b2l[kf][cf], acc2[cf], 0, 0, 0);
                }
            // scatter-add: m_f (dir=0) -> to, m_r (dir=1) -> from
            const int r0 = rg * 32 + rf * 16 + ((l >> 4) << 2);
            const int e0 = (tile * 64 + r0) >> 1;
            int dst[4];
            dst[0] = sm.run.et[e0];
            dst[1] = sm.run.ef[e0];
            dst[2] = sm.run.et[e0 + 1];
            dst[3] = sm.run.ef[e0 + 1];
#pragma unroll
            for (int q = 0; q < 4; ++q)
#pragma unroll
                for (int cf = 0; cf < 2; ++cf)
                    atomicAdd(&sm.run.ag[dst[q]][cg * 32 + cf * 16 + lr], acc2[cf][q]);
        }
    }
    __syncthreads();
    float* aout = agg + (size_t)g * 128 * 128;
    for (int idx = t; idx < 4096; idx += 512)
        ((float4*)aout)[idx] = ((const float4*)sm.run.ag)[idx];
}

// ---------------- per-pair: sim -> sinkhorn -> T-apply -> store (+score) ----------------
__global__ __launch_bounds__(256) void sink_kernel(
    const float* __restrict__ tbuf, const float* __restrict__ h,
    float* __restrict__ store, float* __restrict__ scores, int do_score) {
    __shared__ float la[128][128];      // 64 KB: log_a then T
    __shared__ float ub[2 * 128 * 66];  // union: (tq,tc)[128][33] then (hq,hc)[128][66]
    __shared__ float pm[256], ps[256];
    const int p = blockIdx.x, t = threadIdx.x;

    const float* tq_src = tbuf + (size_t)(2 * p)     * 128 * 32;
    const float* tc_src = tbuf + (size_t)(2 * p + 1) * 128 * 32;
    for (int idx = t; idx < 4096; idx += 256) {
        int i = idx >> 5, k = idx & 31;
        ub[i * 33 + k]            = tq_src[idx];
        ub[128 * 33 + i * 33 + k] = tc_src[idx];
    }
    __syncthreads();

    for (int idx = t; idx < 16384; idx += 256) {
        int i = idx >> 7, j = idx & 127;
        float acc = 0.f;
#pragma unroll
        for (int k = 0; k < 32; ++k)
            acc = fmaf(ub[i * 33 + k], ub[128 * 33 + j * 33 + k], acc);
        la[i][j] = acc * 10.f;   // 1/TEMP
    }
    __syncthreads();

    const int w = t >> 6, l = t & 63;
    for (int iter = 0; iter < SINKI; ++iter) {
        for (int r = w; r < 128; r += 4) {
            float a0 = la[r][l], a1 = la[r][l + 64];
            float mx = fmaxf(a0, a1);
#pragma unroll
            for (int off = 32; off >= 1; off >>= 1) mx = fmaxf(mx, __shfl_xor(mx, off));
            float s = __expf(a0 - mx) + __expf(a1 - mx);
#pragma unroll
            for (int off = 32; off >= 1; off >>= 1) s += __shfl_xor(s, off);
            float lse = mx + __logf(s);
            la[r][l]      = a0 - lse;
            la[r][l + 64] = a1 - lse;
        }
        __syncthreads();
        const int j = t & 127, hh = t >> 7, i0 = hh * 64;
        float mx = -INFINITY;
        for (int i = i0; i < i0 + 64; ++i) mx = fmaxf(mx, la[i][j]);
        pm[t] = mx;
        __syncthreads();
        const float M = fmaxf(pm[j], pm[128 + j]);
        float s = 0.f;
        for (int i = i0; i < i0 + 64; ++i) s += __expf(la[i][j] - M);
        ps[t] = s;
        __syncthreads();
        const float lse = M + __logf(ps[j] + ps[128 + j]);
        for (int i = i0; i < i0 + 64; ++i) la[i][j] -= lse;
        __syncthreads();
    }

    for (int idx = t; idx < 16384; idx += 256)
        ((float*)la)[idx] = __expf(((float*)la)[idx]);
    const float* hq_src = h + (size_t)(2 * p)     * 128 * 64;
    const float* hc_src = h + (size_t)(2 * p + 1) * 128 * 64;
    for (int idx = t; idx < 8192; idx += 256) {
        int i = idx >> 6, d = idx & 63;
        ub[i * 66 + d]            = hq_src[idx];
        ub[128 * 66 + i * 66 + d] = hc_src[idx];
    }
    __syncthreads();

    float sc = 0.f;
    float* store_q = store + (size_t)(2 * p)     * 128 * 64;
    float* store_c = store + (size_t)(2 * p + 1) * 128 * 64;
    for (int idx = t; idx < 8192; idx += 256) {
        int i = idx >> 6, d = idx & 63;
        float acc = 0.f;
#pragma unroll 8
        for (int j = 0; j < 128; ++j)
            acc = fmaf(la[i][j], ub[128 * 66 + j * 66 + d], acc);
        store_q[idx] = acc;
        if (do_score) sc += fmaxf(ub[i * 66 + d] - acc, 0.f);
    }
    for (int idx = t; idx < 8192; idx += 256) {
        int j = idx >> 6, d = idx & 63;
        float acc = 0.f;
#pragma unroll 8
        for (int i = 0; i < 128; ++i)
            acc = fmaf(la[i][j], ub[i * 66 + d], acc);
        store_c[idx] = acc;
    }
    if (do_score) {
#pragma unroll
        for (int off = 32; off >= 1; off >>= 1) sc += __shfl_xor(sc, off);
        if (l == 0) pm[w] = sc;
        __syncthreads();
        if (t == 0) scores[p] = -(pm[0] + pm[1] + pm[2] + pm[3]);
    }
}

extern "C" void kernel_launch(void* const* d_in, const int* in_sizes, int n_in,
                              void* d_out, int out_size, void* d_ws, size_t ws_size,
                              hipStream_t stream) {
    const float* node_features = (const float*)d_in[0];
    const float* edge_features = (const float*)d_in[1];
    const float* W_enc_n = (const float*)d_in[2];
    const float* b_enc_n = (const float*)d_in[3];
    const float* W_enc_e = (const float*)d_in[4];
    const float* b_enc_e = (const float*)d_in[5];
    const float* W_c1 = (const float*)d_in[6];
    const float* b_c1 = (const float*)d_in[7];
    const float* W_c2 = (const float*)d_in[8];
    const float* b_c2 = (const float*)d_in[9];
    const float* W_m1 = (const float*)d_in[10];
    const float* b_m1 = (const float*)d_in[11];
    const float* W_m2 = (const float*)d_in[12];
    const float* b_m2 = (const float*)d_in[13];
    const float* W_u1 = (const float*)d_in[14];
    const float* b_u1 = (const float*)d_in[15];
    const float* W_u2 = (const float*)d_in[16];
    const float* b_u2 = (const float*)d_in[17];
    const float* W_t1 = (const float*)d_in[18];
    const float* b_t1 = (const float*)d_in[19];
    const float* W_t2 = (const float*)d_in[20];
    const float* b_t2 = (const float*)d_in[21];
    const int* from_idx = (const int*)d_in[22];
    const int* to_idx   = (const int*)d_in[23];
    float* scores = (float*)d_out;

    char* ws = (char*)d_ws;
    size_t off = 0;
    auto alloc = [&](size_t nfloats) { float* pp = (float*)(ws + off); off += nfloats * sizeof(float); return pp; };
    float* h    = alloc((size_t)NNODE * 64);
    float* st   = alloc((size_t)NNODE * 64);
    float* cbuf = alloc((size_t)NNODE * 64);
    float* aggb = alloc((size_t)NNODE * 128);
    float* tb   = alloc((size_t)NNODE * 32);
    float* eenc = alloc((size_t)NEDGE * 32);
    (void)ws_size; (void)in_sizes; (void)n_in; (void)out_size;

    hipMemsetAsync(st, 0, (size_t)NNODE * 64 * sizeof(float), stream);
    enc_kernel<16, 64><<<(NNODE * 64 + 255) / 256, 256, 0, stream>>>(node_features, W_enc_n, b_enc_n, h, NNODE);
    enc_kernel<8, 32><<<(NEDGE * 32 + 255) / 256, 256, 0, stream>>>(edge_features, W_enc_e, b_enc_e, eenc, NEDGE);

    for (int it = 0; it < NPROP; ++it) {
        mlp2_kernel<64, 64, 128, 64><<<NNODE / 64, 256, 0, stream>>>(h, st, W_c1, b_c1, W_c2, b_c2, cbuf);
        msg_kernel<<<NGRAPH, 512, 0, stream>>>(cbuf, eenc, from_idx, to_idx, W_m1, b_m1, W_m2, b_m2, aggb);
        mlp2_kernel<64, 128, 128, 64><<<NNODE / 64, 256, 0, stream>>>(cbuf, aggb, W_u1, b_u1, W_u2, b_u2, h);
        mlp2_kernel<64, 0, 32, 32><<<NNODE / 64, 256, 0, stream>>>(h, nullptr, W_t1, b_t1, W_t2, b_t2, tb);
        sink_kernel<<<256, 256, 0, stream>>>(tb, h, st, scores, it == NPROP - 1 ? 1 : 0);
    }
}

// Round 6
// 8209.756 us; speedup vs baseline: 3.4666x; 1.1322x over previous
//
#include <hip/hip_runtime.h>
#include <hip/hip_bf16.h>

#define NNODE  65536   // 2*B*S
#define NEDGE  524288  // 2*B*EPG
#define NGRAPH 512     // 2*B
#define EPG    1024
#define NPROP  5
#define SINKI  20

typedef __attribute__((ext_vector_type(4))) float f32x4;
typedef __attribute__((ext_vector_type(8))) _Float16 f16x8;

static __device__ __forceinline__ void split2(float v, _Float16& h, _Float16& l) {
    h = (_Float16)v;
    l = (_Float16)(v - (float)h);
}

static __device__ __forceinline__ unsigned packsplit(float v) {
    _Float16 h = (_Float16)v;
    _Float16 lo2 = (_Float16)(v - (float)h);
    union { _Float16 f; unsigned short s; } uh, ul;
    uh.f = h; ul.f = lo2;
    return (unsigned)uh.s | ((unsigned)ul.s << 16);
}

static __device__ __forceinline__ void unpack8(uint4 a, uint4 b, f16x8& h, f16x8& l) {
    union { unsigned u[4]; f16x8 v; } H, L;
    H.u[0] = (a.x & 0xffffu) | (a.y << 16);
    H.u[1] = (a.z & 0xffffu) | (a.w << 16);
    H.u[2] = (b.x & 0xffffu) | (b.y << 16);
    H.u[3] = (b.z & 0xffffu) | (b.w << 16);
    L.u[0] = (a.x >> 16) | (a.y & 0xffff0000u);
    L.u[1] = (a.z >> 16) | (a.w & 0xffff0000u);
    L.u[2] = (b.x >> 16) | (b.y & 0xffff0000u);
    L.u[3] = (b.z >> 16) | (b.w & 0xffff0000u);
    h = H.v; l = L.v;
}

// ---------------- single-layer encoder: y = x@W + b (f32 out) ----------------
template<int IN, int OUT>
__global__ void enc_kernel(const float* __restrict__ x, const float* __restrict__ W,
                           const float* __restrict__ b, float* __restrict__ y, int rows) {
    int idx = blockIdx.x * blockDim.x + threadIdx.x;
    if (idx >= rows * OUT) return;
    int r = idx / OUT, o = idx % OUT;
    const float* xr = x + (size_t)r * IN;
    float acc = b[o];
#pragma unroll
    for (int k = 0; k < IN; ++k) acc = fmaf(xr[k], W[k * OUT + o], acc);
    y[idx] = acc;
}

// ---------------- encoder emitting pre-split hi/lo f16 planes ----------------
template<int IN, int OUT>
__global__ void enc_split_kernel(const float* __restrict__ x, const float* __restrict__ W,
                                 const float* __restrict__ b,
                                 _Float16* __restrict__ yh, _Float16* __restrict__ yl, int rows) {
    int idx = blockIdx.x * blockDim.x + threadIdx.x;
    if (idx >= rows * OUT) return;
    int r = idx / OUT, o = idx % OUT;
    const float* xr = x + (size_t)r * IN;
    float acc = b[o];
#pragma unroll
    for (int k = 0; k < IN; ++k) acc = fmaf(xr[k], W[k * OUT + o], acc);
    _Float16 h, l; split2(acc, h, l);
    yh[idx] = h; yl[idx] = l;
}

// ---------------- W [K][C] f32 -> W^T hi/lo f16 planes [C][K] ----------------
__global__ void splitT_kernel(const float* __restrict__ W, _Float16* __restrict__ Wh,
                              _Float16* __restrict__ Wl, int K, int C) {
    int idx = blockIdx.x * blockDim.x + threadIdx.x;
    if (idx >= K * C) return;
    int k = idx / C, cc = idx % C;
    _Float16 h, l; split2(W[idx], h, l);
    Wh[(size_t)cc * K + k] = h;
    Wl[(size_t)cc * K + k] = l;
}

// ---------------- 2-layer MLP, f32 VALU (round-3 arithmetic, slimmed LDS) ----------------
// TR=32 rows/block -> xs+hs <= 40KB -> 4-5 blocks/CU (vs round-3's 1).
template<int IN1, int IN2, int HID, int OUT>
__global__ __launch_bounds__(256) void mlp2_kernel(
    const float* __restrict__ x1, const float* __restrict__ x2,
    const float* __restrict__ W1, const float* __restrict__ b1,
    const float* __restrict__ W2, const float* __restrict__ b2,
    float* __restrict__ y) {
    constexpr int IN = IN1 + IN2;
    constexpr int TR = 32;
    __shared__ float xs[TR][IN];
    __shared__ float hs[TR][HID];
    const int t = threadIdx.x;
    const int row0 = blockIdx.x * TR;

    constexpr int INQ = IN / 4;
    for (int idx = t; idx < TR * INQ; idx += 256) {
        int r = idx / INQ, k0 = (idx % INQ) * 4;
        float4 v;
        if (IN2 == 0 || k0 < IN1) v = *(const float4*)(x1 + (size_t)(row0 + r) * IN1 + k0);
        else                      v = *(const float4*)(x2 + (size_t)(row0 + r) * IN2 + (k0 - IN1));
        *(float4*)&xs[r][k0] = v;
    }
    __syncthreads();

    constexpr int HQ = HID / 4;
    for (int idx = t; idx < TR * HQ; idx += 256) {
        int r = idx / HQ, j0 = (idx % HQ) * 4;
        float a0 = b1[j0], a1 = b1[j0+1], a2 = b1[j0+2], a3 = b1[j0+3];
        const float* wp = W1 + j0;
#pragma unroll 8
        for (int k = 0; k < IN; ++k) {
            float xv = xs[r][k];
            float4 w = *(const float4*)(wp + k * HID);
            a0 = fmaf(xv, w.x, a0); a1 = fmaf(xv, w.y, a1);
            a2 = fmaf(xv, w.z, a2); a3 = fmaf(xv, w.w, a3);
        }
        *(float4*)&hs[r][j0] = make_float4(fmaxf(a0, 0.f), fmaxf(a1, 0.f),
                                           fmaxf(a2, 0.f), fmaxf(a3, 0.f));
    }
    __syncthreads();

    constexpr int OQ = OUT / 4;
    for (int idx = t; idx < TR * OQ; idx += 256) {
        int r = idx / OQ, d0 = (idx % OQ) * 4;
        float a0 = b2[d0], a1 = b2[d0+1], a2 = b2[d0+2], a3 = b2[d0+3];
        const float* wp = W2 + d0;
#pragma unroll 8
        for (int k = 0; k < HID; ++k) {
            float hv = hs[r][k];
            float4 w = *(const float4*)(wp + k * OUT);
            a0 = fmaf(hv, w.x, a0); a1 = fmaf(hv, w.y, a1);
            a2 = fmaf(hv, w.z, a2); a3 = fmaf(hv, w.w, a3);
        }
        *(float4*)(y + (size_t)(row0 + r) * OUT + d0) = make_float4(a0, a1, a2, a3);
    }
}

// ---------------- per-graph message MLP (split-f16 MFMA) + LDS segment-sum ----------------
__global__ __launch_bounds__(512, 2) void msg_kernel(
    const float* __restrict__ c,
    const _Float16* __restrict__ eh, const _Float16* __restrict__ el,
    const int* __restrict__ from_idx, const int* __restrict__ to_idx,
    const _Float16* __restrict__ W1h, const _Float16* __restrict__ W1l, const float* __restrict__ b1,
    const _Float16* __restrict__ W2h, const _Float16* __restrict__ W2l, const float* __restrict__ b2,
    float* __restrict__ agg) {
    __shared__ float ag[128][128];        // 64 KB, atomic column xor-swizzled
    __shared__ _Float16 csh[128 * 64];    // 16 KB
    __shared__ _Float16 csl[128 * 64];    // 16 KB
    __shared__ unsigned Hp[64 * 128];     // 32 KB packed (hi|lo<<16)
    __shared__ int ef[1024], et[1024];    // 8 KB
    const int g = blockIdx.x, t = threadIdx.x;
    const int l = t & 63, wid = t >> 6;
    const int rg = wid >> 2, cg = wid & 3;
    const int lr = l & 15, lk = (l >> 4) * 8;
    const int ebase = g * EPG, nbase = g * 128;

    // W fragments straight from pre-split global planes (L2-hot)
    f16x8 b1h[5][2], b1l[5][2], b2h[4][2], b2l[4][2];
#pragma unroll
    for (int kf = 0; kf < 5; ++kf)
#pragma unroll
        for (int cf = 0; cf < 2; ++cf) {
            int col = cg * 32 + cf * 16 + lr;
            b1h[kf][cf] = *(const f16x8*)&W1h[(size_t)col * 160 + kf * 32 + lk];
            b1l[kf][cf] = *(const f16x8*)&W1l[(size_t)col * 160 + kf * 32 + lk];
        }
#pragma unroll
    for (int kf = 0; kf < 4; ++kf)
#pragma unroll
        for (int cf = 0; cf < 2; ++cf) {
            int col = cg * 32 + cf * 16 + lr;
            b2h[kf][cf] = *(const f16x8*)&W2h[(size_t)col * 128 + kf * 32 + lk];
            b2l[kf][cf] = *(const f16x8*)&W2l[(size_t)col * 128 + kf * 32 + lk];
        }
    const float b1v[2] = { b1[cg * 32 + lr], b1[cg * 32 + 16 + lr] };
    const float b2v[2] = { b2[cg * 32 + lr], b2[cg * 32 + 16 + lr] };

    // stage: zero ag, split c into hi/lo planes, local edge ids
    for (int idx = t; idx < 4096; idx += 512)
        ((float4*)ag)[idx] = make_float4(0.f, 0.f, 0.f, 0.f);
    {
        const float* cblk = c + (size_t)nbase * 64;
        char* chB = (char*)csh; char* clB = (char*)csl;
        for (int idx = t; idx < 8192; idx += 512) {
            int row = idx >> 6, k = idx & 63;
            _Float16 h, lo2; split2(cblk[idx], h, lo2);
            int byte = ((row << 7) | (k << 1)) ^ ((row & 7) << 4);
            *(_Float16*)(chB + byte) = h;
            *(_Float16*)(clB + byte) = lo2;
        }
    }
    for (int idx = t; idx < 1024; idx += 512) {
        ef[idx] = from_idx[ebase + idx] - nbase;
        et[idx] = to_idx[ebase + idx] - nbase;
    }
    __syncthreads();

    char* chB = (char*)csh; char* clB = (char*)csl;

    for (int tile = 0; tile < 32; ++tile) {
        f32x4 acc[2][2];
        // layer 1
#pragma unroll
        for (int rf = 0; rf < 2; ++rf) {
            const int rloc = rg * 32 + rf * 16 + lr;
            const int R = tile * 64 + rloc;
            const int e2 = R >> 1, dir = R & 1;
            const int fi = ef[e2], ti = et[e2];
            const int rA = dir ? ti : fi, rB = dir ? fi : ti;
            const int swA = (rA & 7) << 4, swB = (rB & 7) << 4;
            f16x8 ah[5], al[5];
            ah[0] = *(const f16x8*)(chB + (((rA << 7) | (lk << 1)) ^ swA));
            al[0] = *(const f16x8*)(clB + (((rA << 7) | (lk << 1)) ^ swA));
            ah[1] = *(const f16x8*)(chB + (((rA << 7) | ((32 + lk) << 1)) ^ swA));
            al[1] = *(const f16x8*)(clB + (((rA << 7) | ((32 + lk) << 1)) ^ swA));
            ah[2] = *(const f16x8*)(chB + (((rB << 7) | (lk << 1)) ^ swB));
            al[2] = *(const f16x8*)(clB + (((rB << 7) | (lk << 1)) ^ swB));
            ah[3] = *(const f16x8*)(chB + (((rB << 7) | ((32 + lk) << 1)) ^ swB));
            al[3] = *(const f16x8*)(clB + (((rB << 7) | ((32 + lk) << 1)) ^ swB));
            ah[4] = *(const f16x8*)&eh[(size_t)(ebase + e2) * 32 + lk];
            al[4] = *(const f16x8*)&el[(size_t)(ebase + e2) * 32 + lk];
            acc[rf][0] = (f32x4){b1v[0], b1v[0], b1v[0], b1v[0]};
            acc[rf][1] = (f32x4){b1v[1], b1v[1], b1v[1], b1v[1]};
#pragma unroll
            for (int kf = 0; kf < 5; ++kf)
#pragma unroll
                for (int cf = 0; cf < 2; ++cf) {
                    acc[rf][cf] = __builtin_amdgcn_mfma_f32_16x16x32_f16(ah[kf], b1h[kf][cf], acc[rf][cf], 0, 0, 0);
                    acc[rf][cf] = __builtin_amdgcn_mfma_f32_16x16x32_f16(al[kf], b1h[kf][cf], acc[rf][cf], 0, 0, 0);
                    acc[rf][cf] = __builtin_amdgcn_mfma_f32_16x16x32_f16(ah[kf], b1l[kf][cf], acc[rf][cf], 0, 0, 0);
                }
        }
        __syncthreads();   // prev tile's Hp reads complete
        // relu -> packed Hp (dword-xor swizzle)
#pragma unroll
        for (int rf = 0; rf < 2; ++rf)
#pragma unroll
            for (int cf = 0; cf < 2; ++cf) {
                const int col = cg * 32 + cf * 16 + lr;
#pragma unroll
                for (int q = 0; q < 4; ++q) {
                    const int row = rg * 32 + rf * 16 + (l >> 4) * 4 + q;
                    Hp[(row * 128 + col) ^ ((row & 7) << 2)] = packsplit(fmaxf(acc[rf][cf][q], 0.f));
                }
            }
        __syncthreads();
        // layer 2 + scatter
#pragma unroll
        for (int rf = 0; rf < 2; ++rf) {
            const int row = rg * 32 + rf * 16 + lr;
            const int sw = (row & 7) << 2;
            f32x4 acc2[2];
            acc2[0] = (f32x4){b2v[0], b2v[0], b2v[0], b2v[0]};
            acc2[1] = (f32x4){b2v[1], b2v[1], b2v[1], b2v[1]};
#pragma unroll
            for (int kf = 0; kf < 4; ++kf) {
                const int c0 = kf * 32 + lk;
                uint4 pa = *(const uint4*)&Hp[(row * 128 + c0) ^ sw];
                uint4 pb = *(const uint4*)&Hp[(row * 128 + c0 + 4) ^ sw];
                f16x8 xh, xl; unpack8(pa, pb, xh, xl);
#pragma unroll
                for (int cf = 0; cf < 2; ++cf) {
                    acc2[cf] = __builtin_amdgcn_mfma_f32_16x16x32_f16(xh, b2h[kf][cf], acc2[cf], 0, 0, 0);
                    acc2[cf] = __builtin_amdgcn_mfma_f32_16x16x32_f16(xl, b2h[kf][cf], acc2[cf], 0, 0, 0);
                    acc2[cf] = __builtin_amdgcn_mfma_f32_16x16x32_f16(xh, b2l[kf][cf], acc2[cf], 0, 0, 0);
                }
            }
            const int r0 = rg * 32 + rf * 16 + ((l >> 4) << 2);
            const int e0 = (tile * 64 + r0) >> 1;
            int dst[4] = { et[e0], ef[e0], et[e0 + 1], ef[e0 + 1] };
#pragma unroll
            for (int q = 0; q < 4; ++q)
#pragma unroll
                for (int cf = 0; cf < 2; ++cf) {
                    const int colq = cg * 32 + cf * 16 + lr;
                    atomicAdd(&ag[dst[q]][colq ^ ((dst[q] & 7) << 2)], acc2[cf][q]);
                }
        }
    }
    __syncthreads();
    float* aout = agg + (size_t)g * 128 * 128;
    for (int idx = t; idx < 4096; idx += 512) {
        int row = idx >> 5, c4 = (idx & 31) << 2;
        ((float4*)aout)[idx] = *(const float4*)&ag[row][c4 ^ ((row & 7) << 2)];
    }
}

// ---------------- per-pair: sim -> sinkhorn -> T-apply -> store (+score) ----------------
__global__ __launch_bounds__(512) void sink_kernel(
    const float* __restrict__ tbuf, const float* __restrict__ h,
    float* __restrict__ store, float* __restrict__ scores, int do_score) {
    __shared__ float la[128][128];      // 64 KB: log_a then T
    __shared__ float ub[2 * 128 * 66];  // union: (tq,tc)[128][33] then (hq,hc)[128][66]
    __shared__ float pm[512], ps[512];
    const int p = blockIdx.x, t = threadIdx.x;
    const int w = t >> 6, l = t & 63;

    const float* tq_src = tbuf + (size_t)(2 * p)     * 128 * 32;
    const float* tc_src = tbuf + (size_t)(2 * p + 1) * 128 * 32;
    for (int idx = t; idx < 4096; idx += 512) {
        int i = idx >> 5, k = idx & 31;
        ub[i * 33 + k]            = tq_src[idx];
        ub[128 * 33 + i * 33 + k] = tc_src[idx];
    }
    __syncthreads();

    for (int idx = t; idx < 16384; idx += 512) {
        int i = idx >> 7, j = idx & 127;
        float acc = 0.f;
#pragma unroll
        for (int k = 0; k < 32; ++k)
            acc = fmaf(ub[i * 33 + k], ub[128 * 33 + j * 33 + k], acc);
        la[i][j] = acc * 10.f;   // 1/TEMP
    }
    __syncthreads();

    for (int iter = 0; iter < SINKI; ++iter) {
        for (int r = w; r < 128; r += 8) {
            float a0 = la[r][l], a1 = la[r][l + 64];
            float mx = fmaxf(a0, a1);
#pragma unroll
            for (int off = 32; off >= 1; off >>= 1) mx = fmaxf(mx, __shfl_xor(mx, off));
            float s = __expf(a0 - mx) + __expf(a1 - mx);
#pragma unroll
            for (int off = 32; off >= 1; off >>= 1) s += __shfl_xor(s, off);
            float lse = mx + __logf(s);
            la[r][l]      = a0 - lse;
            la[r][l + 64] = a1 - lse;
        }
        __syncthreads();
        const int j = t & 127, q4 = t >> 7, i0 = q4 * 32;
        float mx = -INFINITY;
        for (int i = i0; i < i0 + 32; ++i) mx = fmaxf(mx, la[i][j]);
        pm[t] = mx;
        __syncthreads();
        const float M = fmaxf(fmaxf(pm[j], pm[j + 128]), fmaxf(pm[j + 256], pm[j + 384]));
        float s = 0.f;
        for (int i = i0; i < i0 + 32; ++i) s += __expf(la[i][j] - M);
        ps[t] = s;
        __syncthreads();
        const float lse = M + __logf(ps[j] + ps[j + 128] + ps[j + 256] + ps[j + 384]);
        for (int i = i0; i < i0 + 32; ++i) la[i][j] -= lse;
        __syncthreads();
    }

    for (int idx = t; idx < 16384; idx += 512)
        ((float*)la)[idx] = __expf(((float*)la)[idx]);
    const float* hq_src = h + (size_t)(2 * p)     * 128 * 64;
    const float* hc_src = h + (size_t)(2 * p + 1) * 128 * 64;
    for (int idx = t; idx < 8192; idx += 512) {
        int i = idx >> 6, d = idx & 63;
        ub[i * 66 + d]            = hq_src[idx];
        ub[128 * 66 + i * 66 + d] = hc_src[idx];
    }
    __syncthreads();

    float sc = 0.f;
    float* store_q = store + (size_t)(2 * p)     * 128 * 64;
    float* store_c = store + (size_t)(2 * p + 1) * 128 * 64;
    for (int idx = t; idx < 8192; idx += 512) {
        int i = idx >> 6, d = idx & 63;
        float acc = 0.f;
#pragma unroll 8
        for (int j = 0; j < 128; ++j)
            acc = fmaf(la[i][j], ub[128 * 66 + j * 66 + d], acc);
        store_q[idx] = acc;
        if (do_score) sc += fmaxf(ub[i * 66 + d] - acc, 0.f);
    }
    for (int idx = t; idx < 8192; idx += 512) {
        int j = idx >> 6, d = idx & 63;
        float acc = 0.f;
#pragma unroll 8
        for (int i = 0; i < 128; ++i)
            acc = fmaf(la[i][j], ub[i * 66 + d], acc);
        store_c[idx] = acc;
    }
    if (do_score) {
#pragma unroll
        for (int off = 32; off >= 1; off >>= 1) sc += __shfl_xor(sc, off);
        if (l == 0) pm[w] = sc;
        __syncthreads();
        if (t == 0) {
            float s8 = 0.f;
#pragma unroll
            for (int i = 0; i < 8; ++i) s8 += pm[i];
            scores[p] = -s8;
        }
    }
}

extern "C" void kernel_launch(void* const* d_in, const int* in_sizes, int n_in,
                              void* d_out, int out_size, void* d_ws, size_t ws_size,
                              hipStream_t stream) {
    const float* node_features = (const float*)d_in[0];
    const float* edge_features = (const float*)d_in[1];
    const float* W_enc_n = (const float*)d_in[2];
    const float* b_enc_n = (const float*)d_in[3];
    const float* W_enc_e = (const float*)d_in[4];
    const float* b_enc_e = (const float*)d_in[5];
    const float* W_c1 = (const float*)d_in[6];
    const float* b_c1 = (const float*)d_in[7];
    const float* W_c2 = (const float*)d_in[8];
    const float* b_c2 = (const float*)d_in[9];
    const float* W_m1 = (const float*)d_in[10];
    const float* b_m1 = (const float*)d_in[11];
    const float* W_m2 = (const float*)d_in[12];
    const float* b_m2 = (const float*)d_in[13];
    const float* W_u1 = (const float*)d_in[14];
    const float* b_u1 = (const float*)d_in[15];
    const float* W_u2 = (const float*)d_in[16];
    const float* b_u2 = (const float*)d_in[17];
    const float* W_t1 = (const float*)d_in[18];
    const float* b_t1 = (const float*)d_in[19];
    const float* W_t2 = (const float*)d_in[20];
    const float* b_t2 = (const float*)d_in[21];
    const int* from_idx = (const int*)d_in[22];
    const int* to_idx   = (const int*)d_in[23];
    float* scores = (float*)d_out;

    char* ws = (char*)d_ws;
    size_t off = 0;
    auto alloc = [&](size_t bytes) { char* p = ws + off; off += (bytes + 255) & ~(size_t)255; return p; };
    float* h    = (float*)alloc((size_t)NNODE * 64 * 4);
    float* st   = (float*)alloc((size_t)NNODE * 64 * 4);
    float* cbuf = (float*)alloc((size_t)NNODE * 64 * 4);
    float* aggb = (float*)alloc((size_t)NNODE * 128 * 4);
    float* tb   = (float*)alloc((size_t)NNODE * 32 * 4);
    _Float16* eench = (_Float16*)alloc((size_t)NEDGE * 32 * 2);
    _Float16* eencl = (_Float16*)alloc((size_t)NEDGE * 32 * 2);
    _Float16* Wm1h = (_Float16*)alloc(160 * 128 * 2);
    _Float16* Wm1l = (_Float16*)alloc(160 * 128 * 2);
    _Float16* Wm2h = (_Float16*)alloc(128 * 128 * 2);
    _Float16* Wm2l = (_Float16*)alloc(128 * 128 * 2);
    (void)ws_size; (void)in_sizes; (void)n_in; (void)out_size;

    hipMemsetAsync(st, 0, (size_t)NNODE * 64 * sizeof(float), stream);
    enc_kernel<16, 64><<<(NNODE * 64 + 255) / 256, 256, 0, stream>>>(node_features, W_enc_n, b_enc_n, h, NNODE);
    enc_split_kernel<8, 32><<<(NEDGE * 32 + 255) / 256, 256, 0, stream>>>(edge_features, W_enc_e, b_enc_e, eench, eencl, NEDGE);
    splitT_kernel<<<(160 * 128 + 255) / 256, 256, 0, stream>>>(W_m1, Wm1h, Wm1l, 160, 128);
    splitT_kernel<<<(128 * 128 + 255) / 256, 256, 0, stream>>>(W_m2, Wm2h, Wm2l, 128, 128);

    for (int it = 0; it < NPROP; ++it) {
        mlp2_kernel<64, 64, 128, 64><<<NNODE / 32, 256, 0, stream>>>(h, st, W_c1, b_c1, W_c2, b_c2, cbuf);
        msg_kernel<<<NGRAPH, 512, 0, stream>>>(
            cbuf, eench, eencl, from_idx, to_idx, Wm1h, Wm1l, b_m1, Wm2h, Wm2l, b_m2, aggb);
        mlp2_kernel<64, 128, 128, 64><<<NNODE / 32, 256, 0, stream>>>(cbuf, aggb, W_u1, b_u1, W_u2, b_u2, h);
        mlp2_kernel<64, 0, 32, 32><<<NNODE / 32, 256, 0, stream>>>(h, nullptr, W_t1, b_t1, W_t2, b_t2, tb);
        sink_kernel<<<256, 512, 0, stream>>>(tb, h, st, scores, it == NPROP - 1 ? 1 : 0);
    }
}